// Round 6
// baseline (207.941 us; speedup 1.0000x reference)
//
#include <hip/hip_runtime.h>
#include <stdint.h>

#define DIMD 1024
#define NH   16
#define DH   64
#define BB   4
#define SS   2048
#define MTOT 8192   // BB*SS

// folded into Q at bf16-conversion: 0.125 (= Dh^-0.5) * log2(e), so P = exp2(S')
static constexpr float QSCALE = 0.18033688011112042f;

typedef unsigned short u16;
typedef __attribute__((ext_vector_type(8))) short bf8;    // 8 x bf16 (4 VGPR)
typedef __attribute__((ext_vector_type(4))) float f4;     // 16x16 C/D frag
typedef __attribute__((ext_vector_type(16))) float f16v;  // 32x32 C/D frag

#if __has_builtin(__builtin_amdgcn_exp2f)
#define EXP2(x) __builtin_amdgcn_exp2f(x)
#else
#define EXP2(x) exp2f(x)
#endif

__device__ inline u16 f2bf(float f) {
    union { float f; uint32_t u; } v; v.f = f;
    uint32_t r = v.u + 0x7fffu + ((v.u >> 16) & 1u);   // RNE
    return (u16)(r >> 16);
}

__device__ inline void gld16(const void* g, void* l) {
    __builtin_amdgcn_global_load_lds(
        (const __attribute__((address_space(1))) uint32_t*)g,
        (__attribute__((address_space(3))) uint32_t*)l, 16, 0, 0);
}

__device__ inline uint32_t cvtpk(float lo, float hi) {
    uint32_t r;
    asm("v_cvt_pk_bf16_f32 %0, %1, %2" : "=v"(r) : "v"(lo), "v"(hi));
    return r;
}

// ---------------- fp32 -> bf16 convert ----------------
__global__ void cvt_bf16(const float* __restrict__ src, u16* __restrict__ dst, int n) {
    int i = (blockIdx.x * blockDim.x + threadIdx.x) * 4;
    if (i >= n) return;
    float4 v = *(const float4*)(src + i);
    ushort4 o;
    o.x = f2bf(v.x); o.y = f2bf(v.y); o.z = f2bf(v.z); o.w = f2bf(v.w);
    *(ushort4*)(dst + i) = o;
}

// ---------------- QKV projection: C = A @ W^T + b ----------------
// z==0: Q * QSCALE -> [B,H,S,Dh];  z==1: K -> [B,H,S,Dh];  z==2: V -> Vt [B,H,Dh,S]
// 1-D grid 1536, XCD-chunked: each XCD sweeps all bm for 3 (bn,z) pairs -> W-panels L2-resident.
__global__ __launch_bounds__(256, 2) void gemm_qkv(
    const u16* __restrict__ xb, const u16* __restrict__ Wb,
    const float* __restrict__ bq, const float* __restrict__ bk, const float* __restrict__ bv,
    u16* __restrict__ qkv, u16* __restrict__ vtb)
{
    __shared__ u16 lA[128 * 64];
    __shared__ u16 lB[128 * 64];
    const int tid = threadIdx.x;

    const int flat = blockIdx.x;                 // 0..1535
    const int swz = (flat & 7) * 192 + (flat >> 3);
    const int bm = swz & 63;
    const int rest = swz >> 6;                   // 0..23
    const int bn = rest & 7, z = rest >> 3;

    const u16* W = Wb + (size_t)z * DIMD * DIMD;
    const float* bias = (z == 0) ? bq : ((z == 1) ? bk : bv);
    u16* outp = qkv + (size_t)z * (size_t)MTOT * DIMD;

    const int lane = tid & 63, w = tid >> 6;
    const int wr = (w >> 1) * 64, wc = (w & 1) * 64;
    f4 acc[4][4] = {};

    const char* Abase = (const char*)xb + (size_t)(bm * 128) * 2048;
    const char* Bbase = (const char*)W + (size_t)(bn * 128) * 2048;

    for (int kt = 0; kt < 16; ++kt) {
        __syncthreads();
        #pragma unroll
        for (int p = 0; p < 4; ++p) {
            int off = (p * 256 + tid) * 16;
            int row = off >> 7, cb = off & 127;
            int scb = cb ^ ((row & 7) << 4);
            gld16(Abase + (size_t)row * 2048 + kt * 128 + scb, (char*)lA + off);
            gld16(Bbase + (size_t)row * 2048 + kt * 128 + scb, (char*)lB + off);
        }
        __syncthreads();
        #pragma unroll
        for (int ks = 0; ks < 2; ++ks) {
            const int cb = ks * 64 + ((lane >> 4) << 4);
            bf8 af[4], bfr[4];
            #pragma unroll
            for (int mi = 0; mi < 4; ++mi) {
                int r = wr + mi * 16 + (lane & 15);
                af[mi] = *(const bf8*)((const char*)lA + r * 128 + (cb ^ ((r & 7) << 4)));
            }
            #pragma unroll
            for (int ni = 0; ni < 4; ++ni) {
                int r = wc + ni * 16 + (lane & 15);
                bfr[ni] = *(const bf8*)((const char*)lB + r * 128 + (cb ^ ((r & 7) << 4)));
            }
            #pragma unroll
            for (int mi = 0; mi < 4; ++mi)
                #pragma unroll
                for (int ni = 0; ni < 4; ++ni)
                    acc[mi][ni] = __builtin_amdgcn_mfma_f32_16x16x32_bf16(af[mi], bfr[ni], acc[mi][ni], 0, 0, 0);
        }
    }

    if (z == 2) {
        // V: write transposed [B,H,Dh,S]; 4 consecutive rows (s) -> ushort4
        #pragma unroll
        for (int ni = 0; ni < 4; ++ni) {
            int col = bn * 128 + wc + ni * 16 + (lane & 15);
            float bi = bias[col];
            int h = col >> 6, dh = col & 63;
            #pragma unroll
            for (int mi = 0; mi < 4; ++mi) {
                int row0 = bm * 128 + wr + mi * 16 + ((lane >> 4) << 2);
                int b = row0 >> 11, s = row0 & 2047;
                ushort4 st;
                st.x = f2bf(acc[mi][ni][0] + bi);
                st.y = f2bf(acc[mi][ni][1] + bi);
                st.z = f2bf(acc[mi][ni][2] + bi);
                st.w = f2bf(acc[mi][ni][3] + bi);
                *(ushort4*)(vtb + ((size_t)(b * NH + h) * DH + dh) * SS + s) = st;
            }
        }
    } else {
        const float mulv = (z == 0) ? QSCALE : 1.0f;
        #pragma unroll
        for (int ni = 0; ni < 4; ++ni) {
            int col = bn * 128 + wc + ni * 16 + (lane & 15);
            float bi = bias[col];
            int h = col >> 6, dh = col & 63;
            #pragma unroll
            for (int mi = 0; mi < 4; ++mi) {
                #pragma unroll
                for (int r = 0; r < 4; ++r) {
                    int row = bm * 128 + wr + mi * 16 + ((lane >> 4) << 2) + r;
                    int b = row >> 11, s = row & 2047;
                    outp[(((size_t)(b * NH + h) * SS + s) << 6) + dh] = f2bf((acc[mi][ni][r] + bi) * mulv);
                }
            }
        }
    }
}

// ---------------- out projection: 1-D grid 512, XCD owns one Wo panel ----------------
__global__ __launch_bounds__(256, 2) void gemm_out(
    const u16* __restrict__ Ab, const u16* __restrict__ Wo,
    const float* __restrict__ bo, float* __restrict__ dout)
{
    __shared__ u16 lA[128 * 64];
    __shared__ u16 lB[128 * 64];
    const int tid = threadIdx.x;

    const int flat = blockIdx.x;                 // 0..511
    const int swz = (flat & 7) * 64 + (flat >> 3);
    const int bm = swz & 63;
    const int bn = swz >> 6;                     // 0..7: one Wo panel per XCD

    const int lane = tid & 63, w = tid >> 6;
    const int wr = (w >> 1) * 64, wc = (w & 1) * 64;
    f4 acc[4][4] = {};
    const char* Abase = (const char*)Ab + (size_t)(bm * 128) * 2048;
    const char* Bbase = (const char*)Wo + (size_t)(bn * 128) * 2048;

    for (int kt = 0; kt < 16; ++kt) {
        __syncthreads();
        #pragma unroll
        for (int p = 0; p < 4; ++p) {
            int off = (p * 256 + tid) * 16;
            int row = off >> 7, cb = off & 127;
            int scb = cb ^ ((row & 7) << 4);
            gld16(Abase + (size_t)row * 2048 + kt * 128 + scb, (char*)lA + off);
            gld16(Bbase + (size_t)row * 2048 + kt * 128 + scb, (char*)lB + off);
        }
        __syncthreads();
        #pragma unroll
        for (int ks = 0; ks < 2; ++ks) {
            const int cb = ks * 64 + ((lane >> 4) << 4);
            bf8 af[4], bfr[4];
            #pragma unroll
            for (int mi = 0; mi < 4; ++mi) {
                int r = wr + mi * 16 + (lane & 15);
                af[mi] = *(const bf8*)((const char*)lA + r * 128 + (cb ^ ((r & 7) << 4)));
            }
            #pragma unroll
            for (int ni = 0; ni < 4; ++ni) {
                int r = wc + ni * 16 + (lane & 15);
                bfr[ni] = *(const bf8*)((const char*)lB + r * 128 + (cb ^ ((r & 7) << 4)));
            }
            #pragma unroll
            for (int mi = 0; mi < 4; ++mi)
                #pragma unroll
                for (int ni = 0; ni < 4; ++ni)
                    acc[mi][ni] = __builtin_amdgcn_mfma_f32_16x16x32_bf16(af[mi], bfr[ni], acc[mi][ni], 0, 0, 0);
        }
    }
    #pragma unroll
    for (int ni = 0; ni < 4; ++ni) {
        int col = bn * 128 + wc + ni * 16 + (lane & 15);
        float bi = bo[col];
        #pragma unroll
        for (int mi = 0; mi < 4; ++mi) {
            #pragma unroll
            for (int r = 0; r < 4; ++r) {
                int row = bm * 128 + wr + mi * 16 + ((lane >> 4) << 2) + r;
                dout[(size_t)row * DIMD + col] = acc[mi][ni][r] + bi;
            }
        }
    }
}

// ---------------- flash attention: 8 waves x 32 q, swapped QK^T, T15 double-pipeline ----------------
// 1-D grid 512, XCD-chunked: each XCD owns 8 complete (b,h) heads -> K/V (4 MB) L2-resident.
__global__ __launch_bounds__(512, 4) void attn_fwd(
    const u16* __restrict__ Q, const u16* __restrict__ K,
    const u16* __restrict__ Vt, u16* __restrict__ O)
{
    __shared__ __align__(16) u16 lK[2][64 * 64];
    __shared__ __align__(16) u16 lV[3][64 * 64];

    const int tid = threadIdx.x;
    const int lane = tid & 63, w = tid >> 6;
    const int hi = lane >> 5, l31 = lane & 31;

    const int flat = blockIdx.x;                 // 0..511
    const int swz = (flat & 7) * 64 + (flat >> 3);
    const int bh = swz >> 3;
    const int qb0 = (swz & 7) * 256;

    const char* Kbase = (const char*)(K + (size_t)bh * SS * DH);
    const char* Vbase = (const char*)(Vt + (size_t)bh * DH * SS);

    // Q B-frag (constant over loop): lane holds Q[q=l31][16*kd + 8*hi + j]
    const int qrow = qb0 + w * 32 + l31;
    const u16* Qp = Q + (size_t)bh * SS * DH + (size_t)qrow * DH;
    bf8 qf[4];
    #pragma unroll
    for (int kd = 0; kd < 4; ++kd)
        qf[kd] = *(const bf8*)(Qp + kd * 16 + hi * 8);

    f16v oacc0 = {}, oacc1 = {};
    float lsum = 0.f;
    bf8 pbv[4];          // packed+swapped P fragments of the PREVIOUS tile

    const int rswz = (l31 & 7) << 4;

    // stage tile t: K -> lK[t&1], V -> lV[vbuf]
    auto stage = [&](int t, int vbuf) {
        int off = tid * 16;
        int row = off >> 7, cb = off & 127;
        int scb = cb ^ ((row & 7) << 4);
        int kv0 = t * 64;
        gld16(Kbase + (size_t)(kv0 + row) * 128 + scb, (char*)lK[t & 1] + off);
        gld16(Vbase + (size_t)row * (SS * 2) + (size_t)kv0 * 2 + scb, (char*)lV[vbuf] + off);
    };

    // S^T = K Q^T from lK buffer
    auto QKfn = [&](const char* lKc, f16v& s0, f16v& s1) {
        __builtin_amdgcn_s_setprio(1);
        #pragma unroll
        for (int kd = 0; kd < 4; ++kd) {
            const int colb = 32 * kd + 16 * hi;
            bf8 kf0 = *(const bf8*)(lKc + l31 * 128 + (colb ^ rswz));
            bf8 kf1 = *(const bf8*)(lKc + (32 + l31) * 128 + (colb ^ rswz));
            s0 = __builtin_amdgcn_mfma_f32_32x32x16_bf16(kf0, qf[kd], s0, 0, 0, 0);
            s1 = __builtin_amdgcn_mfma_f32_32x32x16_bf16(kf1, qf[kd], s1, 0, 0, 0);
        }
        __builtin_amdgcn_s_setprio(0);
    };

    // PV for the tile whose pbv is loaded: O^T += V^T P^T (pure ds_read + MFMA)
    auto PVfn = [&](const char* lVc) {
        __builtin_amdgcn_s_setprio(1);
        #pragma unroll
        for (int ks = 0; ks < 4; ++ks) {
            const int colb = 32 * ks + 16 * hi;
            bf8 vf0 = *(const bf8*)(lVc + l31 * 128 + (colb ^ rswz));
            bf8 vf1 = *(const bf8*)(lVc + (32 + l31) * 128 + (colb ^ rswz));
            oacc0 = __builtin_amdgcn_mfma_f32_32x32x16_bf16(vf0, pbv[ks], oacc0, 0, 0, 0);
            oacc1 = __builtin_amdgcn_mfma_f32_32x32x16_bf16(vf1, pbv[ks], oacc1, 0, 0, 0);
        }
        __builtin_amdgcn_s_setprio(0);
    };

    // softmax finish: P = exp2(S'), accumulate lsum, pack+swap into pbv
    auto SMfn = [&](f16v& s0, f16v& s1) {
        float ps[16];
        #pragma unroll
        for (int i = 0; i < 16; ++i) {
            float e0 = EXP2(s0[i]);
            float e1 = EXP2(s1[i]);
            s0[i] = e0; s1[i] = e1;
            ps[i] = e0 + e1;
        }
        float t0 = (ps[0] + ps[1]) + (ps[2] + ps[3]);
        float t1 = (ps[4] + ps[5]) + (ps[6] + ps[7]);
        float t2 = (ps[8] + ps[9]) + (ps[10] + ps[11]);
        float t3 = (ps[12] + ps[13]) + (ps[14] + ps[15]);
        lsum += (t0 + t1) + (t2 + t3);

        uint32_t wv0[8], wv1[8];
        #pragma unroll
        for (int a = 0; a < 4; ++a) {
            wv0[a * 2 + 0] = cvtpk(s0[4 * a + 0], s0[4 * a + 1]);
            wv0[a * 2 + 1] = cvtpk(s0[4 * a + 2], s0[4 * a + 3]);
            wv1[a * 2 + 0] = cvtpk(s1[4 * a + 0], s1[4 * a + 1]);
            wv1[a * 2 + 1] = cvtpk(s1[4 * a + 2], s1[4 * a + 3]);
        }
        #pragma unroll
        for (int ks = 0; ks < 4; ++ks) {
            const int kss = ks & 1;
            uint32_t w0 = (ks < 2) ? wv0[4 * kss + 0] : wv1[4 * kss + 0];
            uint32_t w1 = (ks < 2) ? wv0[4 * kss + 1] : wv1[4 * kss + 1];
            uint32_t w2 = (ks < 2) ? wv0[4 * kss + 2] : wv1[4 * kss + 2];
            uint32_t w3 = (ks < 2) ? wv0[4 * kss + 3] : wv1[4 * kss + 3];
            asm("v_permlane32_swap_b32 %0, %1" : "+v"(w0), "+v"(w2));
            asm("v_permlane32_swap_b32 %0, %1" : "+v"(w1), "+v"(w3));
            union { uint32_t u[4]; bf8 v; } pb;
            pb.u[0] = w0; pb.u[1] = w1; pb.u[2] = w2; pb.u[3] = w3;
            pbv[ks] = pb.v;
        }
    };

    // prologue: tile 0
    stage(0, 0);
    __syncthreads();
    {
        stage(1, 1);
        f16v s0 = {}, s1 = {};
        QKfn((const char*)lK[0], s0, s1);
        SMfn(s0, s1);
        __syncthreads();
    }

    int vW = 2;   // lV buf for tile t+1  ((t+1)%3 at t=1)
    int vR = 0;   // lV buf for tile t-1  ((t-1)%3 at t=1)
    for (int t = 1; t < SS / 64; ++t) {
        if (t + 1 < SS / 64) stage(t + 1, vW);
        f16v s0 = {}, s1 = {};
        QKfn((const char*)lK[t & 1], s0, s1);   // MFMA: current tile scores
        PVfn((const char*)lV[vR]);              // MFMA: previous tile PV (operands ready)
        SMfn(s0, s1);                           // VALU: finish current tile -> pbv
        __syncthreads();
        vW = (vW == 2) ? 0 : vW + 1;
        vR = (vR == 2) ? 0 : vR + 1;
    }
    PVfn((const char*)lV[vR]);                  // tail: PV of last tile

    // ---- epilogue ----
    const float l = lsum + __shfl_xor(lsum, 32, 64);
    const int b = bh >> 4, h = bh & 15;
    const float inv = 1.f / l;
    u16* orow = O + (((size_t)(b * SS + qrow)) << 10) + h * DH;
    #pragma unroll
    for (int g = 0; g < 4; ++g) {
        ushort4 st0, st1;
        st0.x = f2bf(oacc0[4 * g + 0] * inv); st0.y = f2bf(oacc0[4 * g + 1] * inv);
        st0.z = f2bf(oacc0[4 * g + 2] * inv); st0.w = f2bf(oacc0[4 * g + 3] * inv);
        st1.x = f2bf(oacc1[4 * g + 0] * inv); st1.y = f2bf(oacc1[4 * g + 1] * inv);
        st1.z = f2bf(oacc1[4 * g + 2] * inv); st1.w = f2bf(oacc1[4 * g + 3] * inv);
        *(ushort4*)(orow + 8 * g + 4 * hi) = st0;
        *(ushort4*)(orow + 32 + 8 * g + 4 * hi) = st1;
    }
}

// ---------------- launch ----------------
extern "C" void kernel_launch(void* const* d_in, const int* in_sizes, int n_in,
                              void* d_out, int out_size, void* d_ws, size_t ws_size,
                              hipStream_t stream) {
    const float* x  = (const float*)d_in[0];
    const float* Wq = (const float*)d_in[1];
    const float* bq = (const float*)d_in[2];
    const float* Wk = (const float*)d_in[3];
    const float* bk = (const float*)d_in[4];
    const float* Wv = (const float*)d_in[5];
    const float* bv = (const float*)d_in[6];
    const float* Wo = (const float*)d_in[7];
    const float* bo = (const float*)d_in[8];
    float* out = (float*)d_out;

    u16* wsp = (u16*)d_ws;
    const size_t NX = (size_t)MTOT * DIMD;
    const size_t NW = (size_t)DIMD * DIMD;
    u16* xb   = wsp;                  // reused as attn output after QKV gemm
    u16* Wb   = wsp + NX;
    u16* Qb   = wsp + NX + 4 * NW;    // [B,H,S,Dh], pre-scaled
    u16* Kb   = Qb + NX;              // [B,H,S,Dh]
    u16* Vtb  = Kb + NX;              // [B,H,Dh,S] (written directly by gemm_qkv)
    u16* attn = xb;

    cvt_bf16<<<dim3((int)(NX / 4 / 256)), 256, 0, stream>>>(x, xb, (int)NX);
    cvt_bf16<<<dim3((int)(NW / 4 / 256)), 256, 0, stream>>>(Wq, Wb + 0 * NW, (int)NW);
    cvt_bf16<<<dim3((int)(NW / 4 / 256)), 256, 0, stream>>>(Wk, Wb + 1 * NW, (int)NW);
    cvt_bf16<<<dim3((int)(NW / 4 / 256)), 256, 0, stream>>>(Wv, Wb + 2 * NW, (int)NW);
    cvt_bf16<<<dim3((int)(NW / 4 / 256)), 256, 0, stream>>>(Wo, Wb + 3 * NW, (int)NW);

    gemm_qkv<<<dim3(1536), 256, 0, stream>>>(xb, Wb, bq, bk, bv, Qb, Vtb);
    attn_fwd<<<dim3(512), 512, 0, stream>>>(Qb, Kb, Vtb, attn);
    gemm_out<<<dim3(512), 256, 0, stream>>>(attn, Wb + 3 * NW, bo, out);
}

// Round 7
// 173.579 us; speedup vs baseline: 1.1980x; 1.1980x over previous
//
#include <hip/hip_runtime.h>
#include <stdint.h>

#define DIMD 1024
#define NH   16
#define DH   64
#define BB   4
#define SS   2048
#define MTOT 8192   // BB*SS

// folded into Q at bf16-conversion: 0.125 (= Dh^-0.5) * log2(e), so P = exp2(S')
static constexpr float QSCALE = 0.18033688011112042f;

typedef unsigned short u16;
typedef __attribute__((ext_vector_type(8))) short bf8;    // 8 x bf16 (4 VGPR)
typedef __attribute__((ext_vector_type(4))) float f4;     // 16x16 C/D frag
typedef __attribute__((ext_vector_type(16))) float f16v;  // 32x32 C/D frag

#if __has_builtin(__builtin_amdgcn_exp2f)
#define EXP2(x) __builtin_amdgcn_exp2f(x)
#else
#define EXP2(x) exp2f(x)
#endif

__device__ inline u16 f2bf(float f) {
    union { float f; uint32_t u; } v; v.f = f;
    uint32_t r = v.u + 0x7fffu + ((v.u >> 16) & 1u);   // RNE
    return (u16)(r >> 16);
}

__device__ inline void gld16(const void* g, void* l) {
    __builtin_amdgcn_global_load_lds(
        (const __attribute__((address_space(1))) uint32_t*)g,
        (__attribute__((address_space(3))) uint32_t*)l, 16, 0, 0);
}

__device__ inline uint32_t cvtpk(float lo, float hi) {
    uint32_t r;
    asm("v_cvt_pk_bf16_f32 %0, %1, %2" : "=v"(r) : "v"(lo), "v"(hi));
    return r;
}

// ---------------- fused fp32 -> bf16 convert: x + Wq + Wk + Wv + Wo in ONE dispatch ----------------
// blocks 0..8191: x (8192*1024 elems); blocks 8192..12287: W[wi] (1024 blocks each).
__global__ void cvt_all(const float* __restrict__ x,
                        const float* __restrict__ Wq, const float* __restrict__ Wk,
                        const float* __restrict__ Wv, const float* __restrict__ Wo,
                        u16* __restrict__ xb, u16* __restrict__ Wb)
{
    const int blk = blockIdx.x;
    const float* src;
    u16* dst;
    size_t base;
    if (blk < 8192) {
        src = x; dst = xb; base = (size_t)blk * 1024;
    } else {
        int wi = (blk - 8192) >> 10;        // 0..3
        src = (wi == 0) ? Wq : (wi == 1) ? Wk : (wi == 2) ? Wv : Wo;
        dst = Wb + (size_t)wi * DIMD * DIMD;
        base = (size_t)((blk - 8192) & 1023) * 1024;
    }
    size_t i = base + threadIdx.x * 4;
    float4 v = *(const float4*)(src + i);
    ushort4 o;
    o.x = f2bf(v.x); o.y = f2bf(v.y); o.z = f2bf(v.z); o.w = f2bf(v.w);
    *(ushort4*)(dst + i) = o;
}

// ---------------- QKV projection: C = A @ W^T + b (R3/R5 structure, default 2-D grid) ----------------
// z==0: Q * QSCALE -> [B,H,S,Dh];  z==1: K -> [B,H,S,Dh];  z==2: V -> Vt [B,H,Dh,S]
// NOTE: default dispatch order gives XCD = bm%8 (flat = bm + 64*bn + 512*z) -> A-panels
// are perfectly partitioned per-XCD in L2. Do NOT re-swizzle this grid (R6 regression).
__global__ __launch_bounds__(256, 2) void gemm_qkv(
    const u16* __restrict__ xb, const u16* __restrict__ Wb,
    const float* __restrict__ bq, const float* __restrict__ bk, const float* __restrict__ bv,
    u16* __restrict__ qkv, u16* __restrict__ vtb)
{
    __shared__ u16 lA[128 * 64];
    __shared__ u16 lB[128 * 64];
    const int tid = threadIdx.x;
    const int bm = blockIdx.x, bn = blockIdx.y, z = blockIdx.z;
    const u16* W = Wb + (size_t)z * DIMD * DIMD;
    const float* bias = (z == 0) ? bq : ((z == 1) ? bk : bv);
    u16* outp = qkv + (size_t)z * (size_t)MTOT * DIMD;

    const int lane = tid & 63, w = tid >> 6;
    const int wr = (w >> 1) * 64, wc = (w & 1) * 64;
    f4 acc[4][4] = {};

    const char* Abase = (const char*)xb + (size_t)(bm * 128) * 2048;
    const char* Bbase = (const char*)W + (size_t)(bn * 128) * 2048;

    for (int kt = 0; kt < 16; ++kt) {
        __syncthreads();
        #pragma unroll
        for (int p = 0; p < 4; ++p) {
            int off = (p * 256 + tid) * 16;
            int row = off >> 7, cb = off & 127;
            int scb = cb ^ ((row & 7) << 4);
            gld16(Abase + (size_t)row * 2048 + kt * 128 + scb, (char*)lA + off);
            gld16(Bbase + (size_t)row * 2048 + kt * 128 + scb, (char*)lB + off);
        }
        __syncthreads();
        #pragma unroll
        for (int ks = 0; ks < 2; ++ks) {
            const int cb = ks * 64 + ((lane >> 4) << 4);
            bf8 af[4], bfr[4];
            #pragma unroll
            for (int mi = 0; mi < 4; ++mi) {
                int r = wr + mi * 16 + (lane & 15);
                af[mi] = *(const bf8*)((const char*)lA + r * 128 + (cb ^ ((r & 7) << 4)));
            }
            #pragma unroll
            for (int ni = 0; ni < 4; ++ni) {
                int r = wc + ni * 16 + (lane & 15);
                bfr[ni] = *(const bf8*)((const char*)lB + r * 128 + (cb ^ ((r & 7) << 4)));
            }
            #pragma unroll
            for (int mi = 0; mi < 4; ++mi)
                #pragma unroll
                for (int ni = 0; ni < 4; ++ni)
                    acc[mi][ni] = __builtin_amdgcn_mfma_f32_16x16x32_bf16(af[mi], bfr[ni], acc[mi][ni], 0, 0, 0);
        }
    }

    if (z == 2) {
        // V: write transposed [B,H,Dh,S]; 4 consecutive rows (s) -> ushort4
        #pragma unroll
        for (int ni = 0; ni < 4; ++ni) {
            int col = bn * 128 + wc + ni * 16 + (lane & 15);
            float bi = bias[col];
            int h = col >> 6, dh = col & 63;
            #pragma unroll
            for (int mi = 0; mi < 4; ++mi) {
                int row0 = bm * 128 + wr + mi * 16 + ((lane >> 4) << 2);
                int b = row0 >> 11, s = row0 & 2047;
                ushort4 st;
                st.x = f2bf(acc[mi][ni][0] + bi);
                st.y = f2bf(acc[mi][ni][1] + bi);
                st.z = f2bf(acc[mi][ni][2] + bi);
                st.w = f2bf(acc[mi][ni][3] + bi);
                *(ushort4*)(vtb + ((size_t)(b * NH + h) * DH + dh) * SS + s) = st;
            }
        }
    } else {
        const float mulv = (z == 0) ? QSCALE : 1.0f;
        #pragma unroll
        for (int ni = 0; ni < 4; ++ni) {
            int col = bn * 128 + wc + ni * 16 + (lane & 15);
            float bi = bias[col];
            int h = col >> 6, dh = col & 63;
            #pragma unroll
            for (int mi = 0; mi < 4; ++mi) {
                #pragma unroll
                for (int r = 0; r < 4; ++r) {
                    int row = bm * 128 + wr + mi * 16 + ((lane >> 4) << 2) + r;
                    int b = row >> 11, s = row & 2047;
                    outp[(((size_t)(b * NH + h) * SS + s) << 6) + dh] = f2bf((acc[mi][ni][r] + bi) * mulv);
                }
            }
        }
    }
}

// ---------------- out projection (R3/R5 structure, default 2-D grid) ----------------
__global__ __launch_bounds__(256, 2) void gemm_out(
    const u16* __restrict__ Ab, const u16* __restrict__ Wo,
    const float* __restrict__ bo, float* __restrict__ dout)
{
    __shared__ u16 lA[128 * 64];
    __shared__ u16 lB[128 * 64];
    const int tid = threadIdx.x;
    const int bm = blockIdx.x, bn = blockIdx.y;
    const int lane = tid & 63, w = tid >> 6;
    const int wr = (w >> 1) * 64, wc = (w & 1) * 64;
    f4 acc[4][4] = {};
    const char* Abase = (const char*)Ab + (size_t)(bm * 128) * 2048;
    const char* Bbase = (const char*)Wo + (size_t)(bn * 128) * 2048;

    for (int kt = 0; kt < 16; ++kt) {
        __syncthreads();
        #pragma unroll
        for (int p = 0; p < 4; ++p) {
            int off = (p * 256 + tid) * 16;
            int row = off >> 7, cb = off & 127;
            int scb = cb ^ ((row & 7) << 4);
            gld16(Abase + (size_t)row * 2048 + kt * 128 + scb, (char*)lA + off);
            gld16(Bbase + (size_t)row * 2048 + kt * 128 + scb, (char*)lB + off);
        }
        __syncthreads();
        #pragma unroll
        for (int ks = 0; ks < 2; ++ks) {
            const int cb = ks * 64 + ((lane >> 4) << 4);
            bf8 af[4], bfr[4];
            #pragma unroll
            for (int mi = 0; mi < 4; ++mi) {
                int r = wr + mi * 16 + (lane & 15);
                af[mi] = *(const bf8*)((const char*)lA + r * 128 + (cb ^ ((r & 7) << 4)));
            }
            #pragma unroll
            for (int ni = 0; ni < 4; ++ni) {
                int r = wc + ni * 16 + (lane & 15);
                bfr[ni] = *(const bf8*)((const char*)lB + r * 128 + (cb ^ ((r & 7) << 4)));
            }
            #pragma unroll
            for (int mi = 0; mi < 4; ++mi)
                #pragma unroll
                for (int ni = 0; ni < 4; ++ni)
                    acc[mi][ni] = __builtin_amdgcn_mfma_f32_16x16x32_bf16(af[mi], bfr[ni], acc[mi][ni], 0, 0, 0);
        }
    }
    #pragma unroll
    for (int ni = 0; ni < 4; ++ni) {
        int col = bn * 128 + wc + ni * 16 + (lane & 15);
        float bi = bo[col];
        #pragma unroll
        for (int mi = 0; mi < 4; ++mi) {
            #pragma unroll
            for (int r = 0; r < 4; ++r) {
                int row = bm * 128 + wr + mi * 16 + ((lane >> 4) << 2) + r;
                dout[(size_t)row * DIMD + col] = acc[mi][ni][r] + bi;
            }
        }
    }
}

// ---------------- flash attention: 8 waves x 32 q, swapped QK^T, T15 double-pipeline ----------------
// Per iter t: QK-MFMA[t] ; PV-MFMA[t-1] (operands ready -> fills QK's result latency) ;
// exp/pack VALU[t] -> pbv for next iter. V triple-buffered (stage t+1 while PV reads t-1).
__global__ __launch_bounds__(512, 4) void attn_fwd(
    const u16* __restrict__ Q, const u16* __restrict__ K,
    const u16* __restrict__ Vt, u16* __restrict__ O)
{
    __shared__ __align__(16) u16 lK[2][64 * 64];
    __shared__ __align__(16) u16 lV[3][64 * 64];

    const int tid = threadIdx.x;
    const int lane = tid & 63, w = tid >> 6;
    const int hi = lane >> 5, l31 = lane & 31;
    const int bh = blockIdx.y;
    const int qb0 = blockIdx.x * 256;
    const char* Kbase = (const char*)(K + (size_t)bh * SS * DH);
    const char* Vbase = (const char*)(Vt + (size_t)bh * DH * SS);

    // Q B-frag (constant over loop): lane holds Q[q=l31][16*kd + 8*hi + j]
    const int qrow = qb0 + w * 32 + l31;
    const u16* Qp = Q + (size_t)bh * SS * DH + (size_t)qrow * DH;
    bf8 qf[4];
    #pragma unroll
    for (int kd = 0; kd < 4; ++kd)
        qf[kd] = *(const bf8*)(Qp + kd * 16 + hi * 8);

    f16v oacc0 = {}, oacc1 = {};
    float lsum = 0.f;
    bf8 pbv[4];          // packed+swapped P fragments of the PREVIOUS tile

    const int rswz = (l31 & 7) << 4;

    // stage tile t: K -> lK[t&1], V -> lV[vbuf]
    auto stage = [&](int t, int vbuf) {
        int off = tid * 16;
        int row = off >> 7, cb = off & 127;
        int scb = cb ^ ((row & 7) << 4);
        int kv0 = t * 64;
        gld16(Kbase + (size_t)(kv0 + row) * 128 + scb, (char*)lK[t & 1] + off);
        gld16(Vbase + (size_t)row * (SS * 2) + (size_t)kv0 * 2 + scb, (char*)lV[vbuf] + off);
    };

    // S^T = K Q^T from lK buffer
    auto QKfn = [&](const char* lKc, f16v& s0, f16v& s1) {
        __builtin_amdgcn_s_setprio(1);
        #pragma unroll
        for (int kd = 0; kd < 4; ++kd) {
            const int colb = 32 * kd + 16 * hi;
            bf8 kf0 = *(const bf8*)(lKc + l31 * 128 + (colb ^ rswz));
            bf8 kf1 = *(const bf8*)(lKc + (32 + l31) * 128 + (colb ^ rswz));
            s0 = __builtin_amdgcn_mfma_f32_32x32x16_bf16(kf0, qf[kd], s0, 0, 0, 0);
            s1 = __builtin_amdgcn_mfma_f32_32x32x16_bf16(kf1, qf[kd], s1, 0, 0, 0);
        }
        __builtin_amdgcn_s_setprio(0);
    };

    // PV for the tile whose pbv is loaded: O^T += V^T P^T (pure ds_read + MFMA)
    auto PVfn = [&](const char* lVc) {
        __builtin_amdgcn_s_setprio(1);
        #pragma unroll
        for (int ks = 0; ks < 4; ++ks) {
            const int colb = 32 * ks + 16 * hi;
            bf8 vf0 = *(const bf8*)(lVc + l31 * 128 + (colb ^ rswz));
            bf8 vf1 = *(const bf8*)(lVc + (32 + l31) * 128 + (colb ^ rswz));
            oacc0 = __builtin_amdgcn_mfma_f32_32x32x16_bf16(vf0, pbv[ks], oacc0, 0, 0, 0);
            oacc1 = __builtin_amdgcn_mfma_f32_32x32x16_bf16(vf1, pbv[ks], oacc1, 0, 0, 0);
        }
        __builtin_amdgcn_s_setprio(0);
    };

    // softmax finish: P = exp2(S'), accumulate lsum, pack+swap into pbv
    auto SMfn = [&](f16v& s0, f16v& s1) {
        float ps[16];
        #pragma unroll
        for (int i = 0; i < 16; ++i) {
            float e0 = EXP2(s0[i]);
            float e1 = EXP2(s1[i]);
            s0[i] = e0; s1[i] = e1;
            ps[i] = e0 + e1;
        }
        float t0 = (ps[0] + ps[1]) + (ps[2] + ps[3]);
        float t1 = (ps[4] + ps[5]) + (ps[6] + ps[7]);
        float t2 = (ps[8] + ps[9]) + (ps[10] + ps[11]);
        float t3 = (ps[12] + ps[13]) + (ps[14] + ps[15]);
        lsum += (t0 + t1) + (t2 + t3);

        uint32_t wv0[8], wv1[8];
        #pragma unroll
        for (int a = 0; a < 4; ++a) {
            wv0[a * 2 + 0] = cvtpk(s0[4 * a + 0], s0[4 * a + 1]);
            wv0[a * 2 + 1] = cvtpk(s0[4 * a + 2], s0[4 * a + 3]);
            wv1[a * 2 + 0] = cvtpk(s1[4 * a + 0], s1[4 * a + 1]);
            wv1[a * 2 + 1] = cvtpk(s1[4 * a + 2], s1[4 * a + 3]);
        }
        #pragma unroll
        for (int ks = 0; ks < 4; ++ks) {
            const int kss = ks & 1;
            uint32_t w0 = (ks < 2) ? wv0[4 * kss + 0] : wv1[4 * kss + 0];
            uint32_t w1 = (ks < 2) ? wv0[4 * kss + 1] : wv1[4 * kss + 1];
            uint32_t w2 = (ks < 2) ? wv0[4 * kss + 2] : wv1[4 * kss + 2];
            uint32_t w3 = (ks < 2) ? wv0[4 * kss + 3] : wv1[4 * kss + 3];
            asm("v_permlane32_swap_b32 %0, %1" : "+v"(w0), "+v"(w2));
            asm("v_permlane32_swap_b32 %0, %1" : "+v"(w1), "+v"(w3));
            union { uint32_t u[4]; bf8 v; } pb;
            pb.u[0] = w0; pb.u[1] = w1; pb.u[2] = w2; pb.u[3] = w3;
            pbv[ks] = pb.v;
        }
    };

    // prologue: tile 0
    stage(0, 0);
    __syncthreads();
    {
        stage(1, 1);
        f16v s0 = {}, s1 = {};
        QKfn((const char*)lK[0], s0, s1);
        SMfn(s0, s1);
        __syncthreads();
    }

    int vW = 2;   // lV buf for tile t+1  ((t+1)%3 at t=1)
    int vR = 0;   // lV buf for tile t-1  ((t-1)%3 at t=1)
    for (int t = 1; t < SS / 64; ++t) {
        if (t + 1 < SS / 64) stage(t + 1, vW);
        f16v s0 = {}, s1 = {};
        QKfn((const char*)lK[t & 1], s0, s1);   // MFMA: current tile scores
        PVfn((const char*)lV[vR]);              // MFMA: previous tile PV (operands ready)
        SMfn(s0, s1);                           // VALU: finish current tile -> pbv
        __syncthreads();
        vW = (vW == 2) ? 0 : vW + 1;
        vR = (vR == 2) ? 0 : vR + 1;
    }
    PVfn((const char*)lV[vR]);                  // tail: PV of last tile

    // ---- epilogue ----
    const float l = lsum + __shfl_xor(lsum, 32, 64);
    const int b = bh >> 4, h = bh & 15;
    const float inv = 1.f / l;
    u16* orow = O + (((size_t)(b * SS + qrow)) << 10) + h * DH;
    #pragma unroll
    for (int g = 0; g < 4; ++g) {
        ushort4 st0, st1;
        st0.x = f2bf(oacc0[4 * g + 0] * inv); st0.y = f2bf(oacc0[4 * g + 1] * inv);
        st0.z = f2bf(oacc0[4 * g + 2] * inv); st0.w = f2bf(oacc0[4 * g + 3] * inv);
        st1.x = f2bf(oacc1[4 * g + 0] * inv); st1.y = f2bf(oacc1[4 * g + 1] * inv);
        st1.z = f2bf(oacc1[4 * g + 2] * inv); st1.w = f2bf(oacc1[4 * g + 3] * inv);
        *(ushort4*)(orow + 8 * g + 4 * hi) = st0;
        *(ushort4*)(orow + 32 + 8 * g + 4 * hi) = st1;
    }
}

// ---------------- launch ----------------
extern "C" void kernel_launch(void* const* d_in, const int* in_sizes, int n_in,
                              void* d_out, int out_size, void* d_ws, size_t ws_size,
                              hipStream_t stream) {
    const float* x  = (const float*)d_in[0];
    const float* Wq = (const float*)d_in[1];
    const float* bq = (const float*)d_in[2];
    const float* Wk = (const float*)d_in[3];
    const float* bk = (const float*)d_in[4];
    const float* Wv = (const float*)d_in[5];
    const float* bv = (const float*)d_in[6];
    const float* Wo = (const float*)d_in[7];
    const float* bo = (const float*)d_in[8];
    float* out = (float*)d_out;

    u16* wsp = (u16*)d_ws;
    const size_t NX = (size_t)MTOT * DIMD;
    const size_t NW = (size_t)DIMD * DIMD;
    u16* xb   = wsp;                  // reused as attn output after QKV gemm
    u16* Wb   = wsp + NX;
    u16* Qb   = wsp + NX + 4 * NW;    // [B,H,S,Dh], pre-scaled
    u16* Kb   = Qb + NX;              // [B,H,S,Dh]
    u16* Vtb  = Kb + NX;              // [B,H,Dh,S] (written directly by gemm_qkv)
    u16* attn = xb;

    cvt_all<<<dim3(12288), 256, 0, stream>>>(x, Wq, Wk, Wv, Wo, xb, Wb);

    gemm_qkv<<<dim3(MTOT / 128, DIMD / 128, 3), 256, 0, stream>>>(xb, Wb, bq, bk, bv, Qb, Vtb);
    attn_fwd<<<dim3(SS / 256, BB * NH), 512, 0, stream>>>(Qb, Kb, Vtb, attn);
    gemm_out<<<dim3(MTOT / 128, DIMD / 128), 256, 0, stream>>>(attn, Wb + 3 * NW, bo, out);
}